// Round 1
// baseline (405.079 us; speedup 1.0000x reference)
//
#include <hip/hip_runtime.h>

#define N_ROWS 4096
#define DIM 1024
#define INV_T (1.0f / 0.07f)
#define FP8_SCALE 16.0f
// acc = (16*c1)·(16*c2) = 256*cos; exp2 argument = acc * INV_T * log2(e) / 256
#define EXP_SCALE (INV_T * 1.44269504088896f / 256.0f)
#define BK 128   // fp8 elements per k-tile (= 128 B rows in LDS) = one MFMA-K
#define NJT 16   // number of j-tiles (= grid.x of gemm, 256-wide tiles)

typedef __attribute__((ext_vector_type(4))) float floatx4;
typedef __attribute__((ext_vector_type(4))) int int4x;
typedef __attribute__((ext_vector_type(8))) int int8x;

template <int V> struct ic { static constexpr int v = V; };

// fp32 -> OCP e4m3fn. Prefer the HW packed convert (v_cvt_pk_fp8_f32, RNE).
#if __has_builtin(__builtin_amdgcn_cvt_pk_fp8_f32)
__device__ inline unsigned int pack4_e4m3(float x, float y, float z, float w) {
    int p = __builtin_amdgcn_cvt_pk_fp8_f32(x, y, 0, false);   // low word
    p = __builtin_amdgcn_cvt_pk_fp8_f32(z, w, p, true);        // high word
    return (unsigned int)p;
}
#else
__device__ inline unsigned int f2e4m3(float x) {
    unsigned int u = __float_as_uint(x);
    unsigned int s = (u >> 24) & 0x80u;
    int e = (int)((u >> 23) & 0xffu);
    unsigned int m = u & 0x7fffffu;
    if (e < 121) return s;              // FTZ (|x| < 2^-6)
    unsigned int t = m >> 20;
    unsigned int rest = m & 0xFFFFFu;
    t += (rest > 0x80000u) || (rest == 0x80000u && (t & 1u));  // RNE
    int e8 = e - 120;
    if (t == 8u) { t = 0u; e8 += 1; }
    return s | ((unsigned int)e8 << 3) | t;
}
__device__ inline unsigned int pack4_e4m3(float x, float y, float z, float w) {
    return f2e4m3(x) | (f2e4m3(y) << 8) | (f2e4m3(z) << 16) | (f2e4m3(w) << 24);
}
#endif

// One WAVE per row (4 rows / 256-thread block). Emits fp8 normalized rows
// (scaled by 16) + exact fp32 diagonal logit. Block 0 zeroes out[0].
__global__ __launch_bounds__(256) void k_normalize(
    const float* __restrict__ z1, const float* __restrict__ z2,
    unsigned char* __restrict__ z1f, unsigned char* __restrict__ z2f,
    float* __restrict__ diag, float* __restrict__ out) {
    const int lane = threadIdx.x & 63, wave = threadIdx.x >> 6;
    const int row = blockIdx.x * 4 + wave;

    if (blockIdx.x == 0 && threadIdx.x == 0) out[0] = 0.f;

    const float4* A = reinterpret_cast<const float4*>(z1 + (size_t)row * DIM);
    const float4* B = reinterpret_cast<const float4*>(z2 + (size_t)row * DIM);
    float4 a[4], b[4];
    #pragma unroll
    for (int rep = 0; rep < 4; ++rep) {
        a[rep] = A[lane + 64 * rep];
        b[rep] = B[lane + 64 * rep];
    }

    float s11 = 0.f, s22 = 0.f, s12 = 0.f;
    #pragma unroll
    for (int rep = 0; rep < 4; ++rep) {
        s11 += a[rep].x * a[rep].x + a[rep].y * a[rep].y
             + a[rep].z * a[rep].z + a[rep].w * a[rep].w;
        s22 += b[rep].x * b[rep].x + b[rep].y * b[rep].y
             + b[rep].z * b[rep].z + b[rep].w * b[rep].w;
        s12 += a[rep].x * b[rep].x + a[rep].y * b[rep].y
             + a[rep].z * b[rep].z + a[rep].w * b[rep].w;
    }
    #pragma unroll
    for (int m = 32; m >= 1; m >>= 1) {
        s11 += __shfl_xor(s11, m, 64);
        s22 += __shfl_xor(s22, m, 64);
        s12 += __shfl_xor(s12, m, 64);
    }

    const float n1 = fmaxf(sqrtf(s11), 1e-12f);
    const float n2 = fmaxf(sqrtf(s22), 1e-12f);
    if (lane == 0) diag[row] = s12 / (n1 * n2) * INV_T;
    const float i1 = FP8_SCALE / n1, i2 = FP8_SCALE / n2;

    unsigned int* O1 = reinterpret_cast<unsigned int*>(z1f + (size_t)row * DIM);
    unsigned int* O2 = reinterpret_cast<unsigned int*>(z2f + (size_t)row * DIM);
    #pragma unroll
    for (int rep = 0; rep < 4; ++rep) {
        O1[lane + 64 * rep] = pack4_e4m3(a[rep].x * i1, a[rep].y * i1,
                                         a[rep].z * i1, a[rep].w * i1);
        O2[lane + 64 * rep] = pack4_e4m3(b[rep].x * i2, b[rep].y * i2,
                                         b[rep].z * i2, b[rep].w * i2);
    }
}

// 256x256 8-phase MX-fp8 GEMM (T2 swizzle + T3/T4 counted-vmcnt + T5 setprio).
// 512 threads = 8 waves (2M x 4N). Wave sub-tiles interleaved at half-tile
// granularity: phase quadrant (mh,nh) reads ONLY A-half mh and B-half nh
// (rows mh*128 + wm*64 + t*16, cols nh*128 + wn*32 + n*16), so each of the
// 4 phases per K-tile frees one A-half and one B-half for restaging.
// Region issue schedule: A0(c)@phase 4c-6, B0@4c-5, A1@4c-4, B1@4c-3
// (each = 2 global_load_lds/thread). One s_waitcnt vmcnt(4) per K-tile
// (phases 4 & 8) keeps 2 regions in flight across raw s_barriers — no full
// drain in steady state. vmcnt(0) only in the last iteration (trailing
// issues skipped => counted gate would under-wait). Fused exp+row-sum
// epilogue, per-jT partial P (no atomics).
__global__ __launch_bounds__(512, 2) void k_gemm_sumexp(
    const unsigned char* __restrict__ z1f, const unsigned char* __restrict__ z2f,
    float* __restrict__ P) {
    __shared__ __attribute__((aligned(16))) unsigned char As[2][256 * BK]; // 64 KB
    __shared__ __attribute__((aligned(16))) unsigned char Bs[2][256 * BK]; // 64 KB

    const int iT = blockIdx.y, jT = blockIdx.x;
    const int tid = threadIdx.x;
    const int lane = tid & 63, wave = tid >> 6;   // 8 waves
    const int wm = wave >> 2, wn = wave & 3;      // 2 (M) x 4 (N)
    const int ml = lane & 15, q = lane >> 4;      // MFMA lane decomposition
    const int i0 = iT * 256, j0 = jT * 256;

    // staging geometry: one wave-issue = 1 KB = 8 rows x 8 16B-chunks.
    // LDS slot s of row r holds global chunk s ^ (r&7)  (T2 swizzle).
    const int srow = lane >> 3;
    const int sg = ((lane & 7) ^ srow) * 16;

    floatx4 acc[2][4][2][2];
    #pragma unroll
    for (int mh = 0; mh < 2; ++mh)
        #pragma unroll
        for (int t = 0; t < 4; ++t)
            #pragma unroll
            for (int nh = 0; nh < 2; ++nh)
                #pragma unroll
                for (int n = 0; n < 2; ++n)
                    acc[mh][t][nh][n] = (floatx4){0.f, 0.f, 0.f, 0.f};

    // stage one 128-row region (rbase=0|128) of tile into buffer dbuf:
    // 2 issues/thread, wave-uniform LDS base (linear dest, pre-swizzled src).
    auto stA = [&](int rbase, int tile, int dbuf) {
        #pragma unroll
        for (int u = 0; u < 2; ++u) {
            const int lrow = rbase + wave * 16 + u * 8;
            const unsigned char* g =
                z1f + (size_t)(i0 + lrow + srow) * DIM + tile * BK + sg;
            __builtin_amdgcn_global_load_lds(
                (const __attribute__((address_space(1))) void*)g,
                (__attribute__((address_space(3))) void*)(&As[dbuf][lrow * BK]),
                16, 0, 0);
        }
    };
    auto stB = [&](int rbase, int tile, int dbuf) {
        #pragma unroll
        for (int u = 0; u < 2; ++u) {
            const int lrow = rbase + wave * 16 + u * 8;
            const unsigned char* g =
                z2f + (size_t)(j0 + lrow + srow) * DIM + tile * BK + sg;
            __builtin_amdgcn_global_load_lds(
                (const __attribute__((address_space(1))) void*)g,
                (__attribute__((address_space(3))) void*)(&Bs[dbuf][lrow * BK]),
                16, 0, 0);
        }
    };

    // fragment: lane reads 32 k-bytes [q*32,+32) of row, swizzle-corrected.
    auto ldfrag = [&](const unsigned char* base, int row) -> int8x {
        const int rs = row & 7;
        const unsigned char* rp = base + row * BK;
        int4x lo = *reinterpret_cast<const int4x*>(rp + (((2 * q) ^ rs) * 16));
        int4x hi = *reinterpret_cast<const int4x*>(rp + (((2 * q + 1) ^ rs) * 16));
        return __builtin_shufflevector(lo, hi, 0, 1, 2, 3, 4, 5, 6, 7);
    };

    // one phase: ds_read quadrant frags | issue stage | barrier |
    // lgkmcnt(0) | setprio(1) 8xMFMA setprio(0) | gate | barrier
    auto phase = [&](auto Bc, auto Mc, auto Nc, auto stage, auto gate) {
        constexpr int BUF = decltype(Bc)::v;
        constexpr int MH = decltype(Mc)::v;
        constexpr int NH = decltype(Nc)::v;
        int8x af[4], bf[2];
        #pragma unroll
        for (int t = 0; t < 4; ++t)
            af[t] = ldfrag(&As[BUF][0], MH * 128 + wm * 64 + t * 16 + ml);
        #pragma unroll
        for (int n = 0; n < 2; ++n)
            bf[n] = ldfrag(&Bs[BUF][0], NH * 128 + wn * 32 + n * 16 + ml);
        stage();
        __builtin_amdgcn_s_barrier();
        asm volatile("s_waitcnt lgkmcnt(0)" ::: "memory");
        __builtin_amdgcn_s_setprio(1);
        #pragma unroll
        for (int t = 0; t < 4; ++t)
            #pragma unroll
            for (int n = 0; n < 2; ++n)
                acc[MH][t][NH][n] = __builtin_amdgcn_mfma_scale_f32_16x16x128_f8f6f4(
                    af[t], bf[n], acc[MH][t][NH][n],
                    0 /*fmt A = fp8*/, 0 /*fmt B = fp8*/,
                    0, 0x7F /*scale A = 1.0*/, 0, 0x7F /*scale B = 1.0*/);
        __builtin_amdgcn_s_setprio(0);
        gate();
        __builtin_amdgcn_s_barrier();
    };

    // prologue: tile0 {A0,B0,A1,B1} + tile1 {A0,B0}; allow tile1's 4 loads
    // in flight while guaranteeing tile0 landed.
    stA(0, 0, 0);   stB(0, 0, 0);
    stA(128, 0, 0); stB(128, 0, 0);
    stA(0, 1, 1);   stB(0, 1, 1);
    asm volatile("s_waitcnt vmcnt(4)" ::: "memory");
    __builtin_amdgcn_s_barrier();

    // 8 K-tiles, 2 per iteration (even -> buf0, odd -> buf1).
    #pragma unroll
    for (int t = 0; t < 4; ++t) {
        phase(ic<0>{}, ic<0>{}, ic<0>{}, [&] { stA(128, 2 * t + 1, 1); }, [&] {});
        phase(ic<0>{}, ic<0>{}, ic<1>{}, [&] { stB(128, 2 * t + 1, 1); }, [&] {});
        phase(ic<0>{}, ic<1>{}, ic<0>{}, [&] { if (t < 3) stA(0, 2 * t + 2, 0); }, [&] {});
        phase(ic<0>{}, ic<1>{}, ic<1>{}, [&] { if (t < 3) stB(0, 2 * t + 2, 0); },
              [&] {
                  if (t < 3) asm volatile("s_waitcnt vmcnt(4)" ::: "memory");
                  else       asm volatile("s_waitcnt vmcnt(0)" ::: "memory");
              });
        phase(ic<1>{}, ic<0>{}, ic<0>{}, [&] { if (t < 3) stA(128, 2 * t + 2, 0); }, [&] {});
        phase(ic<1>{}, ic<0>{}, ic<1>{}, [&] { if (t < 3) stB(128, 2 * t + 2, 0); }, [&] {});
        phase(ic<1>{}, ic<1>{}, ic<0>{}, [&] { if (t < 3) stA(0, 2 * t + 3, 1); }, [&] {});
        phase(ic<1>{}, ic<1>{}, ic<1>{}, [&] { if (t < 3) stB(0, 2 * t + 3, 1); },
              [&] {
                  if (t < 3) asm volatile("s_waitcnt vmcnt(4)" ::: "memory");
                  else       asm volatile("s_waitcnt vmcnt(0)" ::: "memory");
              });
    }

    // Epilogue. C/D: col = ml, row-in-16 = q*4+r. Global row =
    // mh*128 + wm*64 + t*16 + q*4 + r; cols covered by (nh,n,ml) = 64/wave.
    // Butterfly over 16 ml-lanes, combine 4 wn-waves via LDS, one store/row.
    float* Pl = reinterpret_cast<float*>(&As[0][0]);  // 4 x 256 floats
    #pragma unroll
    for (int mh = 0; mh < 2; ++mh)
        #pragma unroll
        for (int t = 0; t < 4; ++t)
            #pragma unroll
            for (int r = 0; r < 4; ++r) {
                float v = 0.f;
                #pragma unroll
                for (int nh = 0; nh < 2; ++nh)
                    #pragma unroll
                    for (int n = 0; n < 2; ++n)
                        v += __builtin_amdgcn_exp2f(acc[mh][t][nh][n][r] * EXP_SCALE);
                v += __shfl_xor(v, 1, 64);
                v += __shfl_xor(v, 2, 64);
                v += __shfl_xor(v, 4, 64);
                v += __shfl_xor(v, 8, 64);
                if (ml == 0)
                    Pl[wn * 256 + mh * 128 + wm * 64 + t * 16 + q * 4 + r] = v;
            }
    __syncthreads();
    if (tid < 256) {
        float s = Pl[tid] + Pl[256 + tid] + Pl[512 + tid] + Pl[768 + tid];
        P[jT * N_ROWS + i0 + tid] = s;
    }
}

// 32 blocks x 128 threads: one row per thread, coalesced P reads,
// block partial-sum -> atomicAdd into out[0] (zeroed by k_normalize).
__global__ __launch_bounds__(128) void k_finalize(
    const float* __restrict__ P, const float* __restrict__ diag,
    float* __restrict__ out) {
    const int t = threadIdx.x;
    const int i = blockIdx.x * 128 + t;
    float s = 0.f;
    #pragma unroll
    for (int jt = 0; jt < NJT; ++jt)
        s += P[jt * N_ROWS + i];
    float v = logf(s) - diag[i];
    #pragma unroll
    for (int m = 32; m >= 1; m >>= 1)
        v += __shfl_xor(v, m, 64);
    __shared__ float r[2];
    if ((t & 63) == 0) r[t >> 6] = v;
    __syncthreads();
    if (t == 0) atomicAdd(out, (r[0] + r[1]) * (1.0f / N_ROWS));
}

extern "C" void kernel_launch(void* const* d_in, const int* in_sizes, int n_in,
                              void* d_out, int out_size, void* d_ws, size_t ws_size,
                              hipStream_t stream) {
    const float* z1 = (const float*)d_in[0];
    const float* z2 = (const float*)d_in[1];

    char* ws = (char*)d_ws;
    unsigned char* z1f = (unsigned char*)ws;                                     // 4 MB
    unsigned char* z2f = (unsigned char*)(ws + (size_t)N_ROWS * DIM);            // 4 MB
    float* diag = (float*)(ws + (size_t)N_ROWS * DIM * 2);                       // 16 KB
    float* P = diag + N_ROWS;                                                    // 256 KB

    k_normalize<<<N_ROWS / 4, 256, 0, stream>>>(z1, z2, z1f, z2f, diag,
                                                (float*)d_out);
    k_gemm_sumexp<<<dim3(NJT, 16), 512, 0, stream>>>(z1f, z2f, P);
    k_finalize<<<32, 128, 0, stream>>>(P, diag, (float*)d_out);
}